// Round 3
// baseline (1786.125 us; speedup 1.0000x reference)
//
#include <hip/hip_runtime.h>
#include <hip/hip_bf16.h>
#include <stdint.h>

// FoodRiskGNN: 2-layer GraphSAGE (mean aggr), N=100000, E=1600000, 64->128->64.
// Bucketed (128 nodes/bucket) edge partition + fused LDS-accumulator
// aggregation. No node-granular scatter, no CSR.
//   cast x->bf16 xb
//   hist(bucket) -> scan -> partition pairs into bucket regions (packed u32)
//   agg1 = mean-gather(xb)  [bucketed, LDS f32 acc]
//   h    = relu(agg1@Wl1 + x@Wr1 + b1)      [bf16]
//   y2   = h@Wl2  (linearity: transform before aggregate)  [bf16]
//   agg2 = mean-gather(y2)  [bucketed]
//   out  = sigmoid(agg2 + h@Wr2 + b2)       [f32]

#define NBMAX 784

__device__ __forceinline__ float ldf(const float* p) { return *p; }
__device__ __forceinline__ float ldf(const __hip_bfloat16* p) { return __bfloat162float(*p); }

__device__ __forceinline__ unsigned short bf16u(float f) {
  __hip_bfloat16 h = __float2bfloat16(f);
  return *(unsigned short*)&h;
}

__device__ __forceinline__ void unpack8(uint4 v, float* a) {
  unsigned int u[4] = {v.x, v.y, v.z, v.w};
#pragma unroll
  for (int i = 0; i < 4; ++i) {
    a[2 * i]     = __uint_as_float(u[i] << 16);
    a[2 * i + 1] = __uint_as_float(u[i] & 0xffff0000u);
  }
}

// ---- x (f32) -> xb (bf16), 4 elems/thread ----
__global__ void k_cast(const float* __restrict__ x, unsigned short* __restrict__ xb, int n4) {
  int i = blockIdx.x * blockDim.x + threadIdx.x;
  if (i < n4) {
    float4 v = ((const float4*)x)[i];
    unsigned int u0 = (unsigned int)bf16u(v.x) | ((unsigned int)bf16u(v.y) << 16);
    unsigned int u1 = (unsigned int)bf16u(v.z) | ((unsigned int)bf16u(v.w) << 16);
    ((uint2*)xb)[i] = make_uint2(u0, u1);
  }
}

// ---- bucket histogram (LDS-staged) ----
__global__ __launch_bounds__(512) void k_bhist(const int* __restrict__ dst,
                                               unsigned int* __restrict__ hist, int E, int NB) {
  __shared__ unsigned int lh[NBMAX];
  const int tid = threadIdx.x;
  for (int b = tid; b < NB; b += 512) lh[b] = 0;
  __syncthreads();
  const int e0 = blockIdx.x * 16384;
  const int m = min(16384, E - e0);
  for (int i = tid; i < m; i += 512) atomicAdd(&lh[(unsigned int)dst[e0 + i] >> 7], 1u);
  __syncthreads();
  for (int b = tid; b < NB; b += 512) {
    unsigned int c = lh[b];
    if (c) atomicAdd(&hist[b], c);
  }
}

// ---- scan NB bucket counts -> base (exclusive) + cursor init. 1 wave. ----
__global__ void k_scanb(const unsigned int* __restrict__ hist, unsigned int* __restrict__ base,
                        unsigned int* __restrict__ cursor, int NB) {
  const int lane = threadIdx.x;
  unsigned int running = 0;
  for (int b0 = 0; b0 < NB; b0 += 64) {
    int i = b0 + lane;
    unsigned int v = (i < NB) ? hist[i] : 0;
    unsigned int s = v;
#pragma unroll
    for (int off = 1; off < 64; off <<= 1) {
      unsigned int t = __shfl_up(s, off);
      if (lane >= off) s += t;
    }
    if (i < NB) {
      base[i] = running + s - v;
      cursor[i] = running + s - v;
    }
    running += __shfl(s, 63);
  }
  if (lane == 0) base[NB] = running;
}

// ---- partition edges into bucket regions; payload = src | (dst&127)<<25 ----
__global__ __launch_bounds__(512) void k_part(const int* __restrict__ src,
                                              const int* __restrict__ dst,
                                              unsigned int* __restrict__ cursor,
                                              unsigned int* __restrict__ bkt, int E, int NB) {
  __shared__ unsigned int hist[NBMAX], lbase[NBMAX], gpos[NBMAX], lcur[NBMAX];
  __shared__ unsigned int stage[8192];
  __shared__ unsigned short stageb[8192];
  const int tid = threadIdx.x;
  const int e0 = blockIdx.x * 8192;
  const int m = min(8192, E - e0);
  for (int b = tid; b < NB; b += 512) { hist[b] = 0; lcur[b] = 0; }
  __syncthreads();
  for (int i = tid; i < m; i += 512) atomicAdd(&hist[(unsigned int)dst[e0 + i] >> 7], 1u);
  __syncthreads();
  if (tid < 64) {  // wave-0 exclusive scan of hist -> lbase
    unsigned int running = 0;
    for (int b0 = 0; b0 < NB; b0 += 64) {
      int i = b0 + tid;
      unsigned int v = (i < NB) ? hist[i] : 0;
      unsigned int s = v;
#pragma unroll
      for (int off = 1; off < 64; off <<= 1) {
        unsigned int t = __shfl_up(s, off);
        if (tid >= off) s += t;
      }
      if (i < NB) lbase[i] = running + s - v;
      running += __shfl(s, 63);
    }
  }
  __syncthreads();
  for (int b = tid; b < NB; b += 512) {
    unsigned int c = hist[b];
    gpos[b] = c ? atomicAdd(&cursor[b], c) : 0u;
  }
  for (int i = tid; i < m; i += 512) {
    int d = dst[e0 + i];
    int s = src[e0 + i];
    unsigned int b = (unsigned int)d >> 7;
    unsigned int p = lbase[b] + atomicAdd(&lcur[b], 1u);
    stage[p] = (unsigned int)s | ((unsigned int)(d & 127) << 25);
    stageb[p] = (unsigned short)b;
  }
  __syncthreads();
  for (int i = tid; i < m; i += 512) {
    unsigned int b = stageb[i];
    bkt[gpos[b] + (unsigned int)i - lbase[b]] = stage[i];
  }
}

// ---- bucketed mean-aggregation: block = 128-node bucket, LDS f32 acc ----
__global__ __launch_bounds__(512) void k_aggb(const unsigned short* __restrict__ feat,  // bf16[N][64]
                                              const unsigned int* __restrict__ bkt,
                                              const unsigned int* __restrict__ base,
                                              __hip_bfloat16* __restrict__ out, int N) {
  __shared__ float acc[128 * 64];      // 32 KB
  __shared__ unsigned int cnt[128];
  __shared__ unsigned int pbuf[1024];  // 4 KB
  const int tid = threadIdx.x;
  const int lane = tid & 63, w = tid >> 6;  // 8 waves
  const int nodelo = blockIdx.x << 7;
  for (int i = tid; i < 128 * 64; i += 512) acc[i] = 0.f;
  if (tid < 128) cnt[tid] = 0;
  const int ebeg = (int)base[blockIdx.x], eend = (int)base[blockIdx.x + 1];
  __syncthreads();
  const int half = lane >> 5, ch2 = lane & 31;
  for (int c0 = ebeg; c0 < eend; c0 += 1024) {
    const int m = min(1024, eend - c0);
    for (int i = tid; i < m; i += 512) pbuf[i] = bkt[c0 + i];
    __syncthreads();
#pragma unroll 4
    for (int it = 0; it < 64; ++it) {
      int slot = (w << 7) + (it << 1) + half;  // 2 edges per wave-iter (half-wave each)
      if (slot < m) {
        unsigned int e = pbuf[slot];
        int dl = (int)(e >> 25);
        int srcn = (int)(e & 0x1FFFFFFu);
        unsigned int v = *(const unsigned int*)(feat + ((size_t)srcn << 6) + (ch2 << 1));
        float f0 = __uint_as_float(v << 16);
        float f1 = __uint_as_float(v & 0xffff0000u);
        atomicAdd(&acc[(dl << 6) + (ch2 << 1)], f0);
        atomicAdd(&acc[(dl << 6) + (ch2 << 1) + 1], f1);
        if (ch2 == 0) atomicAdd(&cnt[dl], 1u);
      }
    }
    __syncthreads();
  }
  unsigned int* o32 = (unsigned int*)out;
  for (int i = tid; i < 128 * 32; i += 512) {
    int r = i >> 5, c2 = i & 31;
    int node = nodelo + r;
    if (node < N) {
      unsigned int k = cnt[r];
      float sc = k ? 1.f / (float)k : 0.f;
      float a0 = acc[(r << 6) + (c2 << 1)] * sc;
      float a1 = acc[(r << 6) + (c2 << 1) + 1] * sc;
      o32[((size_t)node << 5) + c2] = (unsigned int)bf16u(a0) | ((unsigned int)bf16u(a1) << 16);
    }
  }
}

// ---- weight transposes ----
__global__ void k_transpose(const float* __restrict__ A, const float* __restrict__ B,
                            const float* __restrict__ C, const float* __restrict__ D,
                            float* __restrict__ AT, float* __restrict__ BT,
                            float* __restrict__ CT, float* __restrict__ DT) {
  int i = blockIdx.x * blockDim.x + threadIdx.x;
  if (i < 64 * 128) {
    int k = i >> 7, j = i & 127;  // A,B: [64][128]
    AT[j * 64 + k] = A[i];
    BT[j * 64 + k] = B[i];
    int k2 = i >> 6, j2 = i & 63;  // C,D: [128][64]
    CT[j2 * 128 + k2] = C[i];
    DT[j2 * 128 + k2] = D[i];
  }
}

// h = relu(agg1@Wl1 + x@Wr1 + b1). lane = node (64-node tile), wave owns 32 of 128 outputs.
__global__ __launch_bounds__(256) void k_gemm1(const float* __restrict__ x,
                                               const __hip_bfloat16* __restrict__ agg1,
                                               const float* __restrict__ WlT,
                                               const float* __restrict__ WrT,
                                               const float* __restrict__ b1,
                                               __hip_bfloat16* __restrict__ h, int n) {
  __shared__ __align__(16) __hip_bfloat16 sO[64][130];
  const int lane = threadIdx.x & 63;
  const int w = __builtin_amdgcn_readfirstlane((int)(threadIdx.x >> 6));
  const int n0 = blockIdx.x * 64;
  const int node = (n0 + lane < n) ? (n0 + lane) : (n - 1);

  float a[64], xr[64];
  {
    const uint4* pa = (const uint4*)(agg1 + (size_t)node * 64);
#pragma unroll
    for (int c = 0; c < 8; ++c) unpack8(pa[c], &a[c * 8]);
    const float4* px = (const float4*)(x + (size_t)node * 64);
#pragma unroll
    for (int c = 0; c < 16; ++c) {
      float4 v = px[c];
      xr[4 * c] = v.x; xr[4 * c + 1] = v.y; xr[4 * c + 2] = v.z; xr[4 * c + 3] = v.w;
    }
  }
  const int j0 = w * 32;
  for (int jj = 0; jj < 32; jj += 2) {
    const int j = j0 + jj;  // wave-uniform -> weight s_loads
    const float* wl0 = WlT + j * 64;
    const float* wr0 = WrT + j * 64;
    const float* wl1 = WlT + (j + 1) * 64;
    const float* wr1 = WrT + (j + 1) * 64;
    float acc0 = b1[j], acc1 = b1[j + 1];
#pragma unroll
    for (int k = 0; k < 64; ++k) {
      acc0 += a[k] * wl0[k] + xr[k] * wr0[k];
      acc1 += a[k] * wl1[k] + xr[k] * wr1[k];
    }
    sO[lane][j]     = __float2bfloat16(fmaxf(acc0, 0.f));
    sO[lane][j + 1] = __float2bfloat16(fmaxf(acc1, 0.f));
  }
  __syncthreads();
#pragma unroll
  for (int it = 0; it < 16; ++it) {
    int idx = it * 256 + threadIdx.x;
    int r = idx >> 6, c = idx & 63;
    int nn = n0 + r;
    if (nn < n)
      *(uint32_t*)((char*)(h + (size_t)nn * 128) + c * 4) =
          *(uint32_t*)((char*)&sO[r][0] + c * 4);
  }
}

// y2 = h@Wl2 (128->64). lane = node, wave owns 16 of 64 outputs.
__global__ __launch_bounds__(256) void k_gemm2(const __hip_bfloat16* __restrict__ h,
                                               const float* __restrict__ WT,
                                               __hip_bfloat16* __restrict__ y2, int n) {
  __shared__ __align__(16) __hip_bfloat16 sO[64][66];
  const int lane = threadIdx.x & 63;
  const int w = __builtin_amdgcn_readfirstlane((int)(threadIdx.x >> 6));
  const int n0 = blockIdx.x * 64;
  const int node = (n0 + lane < n) ? (n0 + lane) : (n - 1);

  float a[128];
  const uint4* p = (const uint4*)(h + (size_t)node * 128);
#pragma unroll
  for (int c = 0; c < 16; ++c) unpack8(p[c], &a[c * 8]);

  const int j0 = w * 16;
  for (int jj = 0; jj < 16; jj += 2) {
    int j = j0 + jj;
    const float* w0 = WT + j * 128;
    const float* w1 = WT + (j + 1) * 128;
    float acc0 = 0.f, acc1 = 0.f;
#pragma unroll
    for (int k = 0; k < 128; ++k) { acc0 += a[k] * w0[k]; acc1 += a[k] * w1[k]; }
    sO[lane][j]     = __float2bfloat16(acc0);
    sO[lane][j + 1] = __float2bfloat16(acc1);
  }
  __syncthreads();
#pragma unroll
  for (int it = 0; it < 8; ++it) {
    int idx = it * 256 + threadIdx.x;
    int r = idx >> 5, c = idx & 31;
    int nn = n0 + r;
    if (nn < n)
      *(uint32_t*)((char*)(y2 + (size_t)nn * 64) + c * 4) =
          *(uint32_t*)((char*)&sO[r][0] + c * 4);
  }
}

// out = sigmoid(agg2 + h@Wr2 + b2). lane = node, wave owns 16 of 64 outputs.
__global__ __launch_bounds__(256) void k_final(const __hip_bfloat16* __restrict__ h,
                                               const __hip_bfloat16* __restrict__ agg2,
                                               const float* __restrict__ WT,
                                               const float* __restrict__ b2,
                                               float* __restrict__ out, int n) {
  __shared__ float sO[64][65];
  const int lane = threadIdx.x & 63;
  const int w = __builtin_amdgcn_readfirstlane((int)(threadIdx.x >> 6));
  const int n0 = blockIdx.x * 64;
  const int node = (n0 + lane < n) ? (n0 + lane) : (n - 1);

  float a[128];
  const uint4* p = (const uint4*)(h + (size_t)node * 128);
#pragma unroll
  for (int c = 0; c < 16; ++c) unpack8(p[c], &a[c * 8]);

  const int j0 = w * 16;
  for (int jj = 0; jj < 16; jj += 2) {
    int j = j0 + jj;
    const float* w0 = WT + j * 128;
    const float* w1 = WT + (j + 1) * 128;
    float acc0 = b2[j] + ldf(agg2 + (size_t)node * 64 + j);
    float acc1 = b2[j + 1] + ldf(agg2 + (size_t)node * 64 + j + 1);
#pragma unroll
    for (int k = 0; k < 128; ++k) { acc0 += a[k] * w0[k]; acc1 += a[k] * w1[k]; }
    sO[lane][j]     = 1.f / (1.f + __expf(-acc0));
    sO[lane][j + 1] = 1.f / (1.f + __expf(-acc1));
  }
  __syncthreads();
#pragma unroll
  for (int it = 0; it < 16; ++it) {
    int idx = it * 256 + threadIdx.x;
    int r = idx >> 6, c = idx & 63;
    int nn = n0 + r;
    if (nn < n) out[(size_t)nn * 64 + c] = sO[r][c];
  }
}

extern "C" void kernel_launch(void* const* d_in, const int* in_sizes, int n_in,
                              void* d_out, int out_size, void* d_ws, size_t ws_size,
                              hipStream_t stream) {
  const float* x   = (const float*)d_in[0];
  const int*   ei  = (const int*)d_in[1];
  const float* Wl1 = (const float*)d_in[2];
  const float* Wr1 = (const float*)d_in[3];
  const float* b1  = (const float*)d_in[4];
  const float* Wl2 = (const float*)d_in[5];
  const float* Wr2 = (const float*)d_in[6];
  const float* b2  = (const float*)d_in[7];
  float* out = (float*)d_out;

  const int N = in_sizes[0] / 64;
  const int E = in_sizes[1] / 2;
  int NB = (N + 127) >> 7;  // 128 nodes per bucket
  if (NB > NBMAX) NB = NBMAX;  // safety clamp (N<=100352 expected)
  const int* src = ei;
  const int* dst = ei + E;

  char* wp = (char*)d_ws;
  auto take = [&](size_t bytes) {
    char* p = wp;
    wp += (bytes + 255) & ~(size_t)255;
    return p;
  };
  unsigned int* hist   = (unsigned int*)take((size_t)NBMAX * 4);
  unsigned int* base   = (unsigned int*)take((size_t)(NBMAX + 1) * 4);
  unsigned int* cursor = (unsigned int*)take((size_t)NBMAX * 4);
  unsigned int* bkt    = (unsigned int*)take((size_t)E * 4);
  float* WlT  = (float*)take(64 * 128 * 4);
  float* WrT  = (float*)take(64 * 128 * 4);
  float* W2lT = (float*)take(128 * 64 * 4);
  float* W2rT = (float*)take(128 * 64 * 4);
  unsigned short* xb = (unsigned short*)take((size_t)N * 64 * 2);  // bf16 x; reused as y2
  __hip_bfloat16* agg = (__hip_bfloat16*)take((size_t)N * 64 * 2);
  __hip_bfloat16* h   = (__hip_bfloat16*)take((size_t)N * 128 * 2);
  __hip_bfloat16* y2  = (__hip_bfloat16*)xb;  // alias: xb dead after agg1

  hipMemsetAsync(hist, 0, (size_t)NBMAX * 4, stream);

  const int n4 = N * 16;  // N*64/4
  k_cast<<<(n4 + 255) / 256, 256, 0, stream>>>(x, xb, n4);
  k_bhist<<<(E + 16383) / 16384, 512, 0, stream>>>(dst, hist, E, NB);
  k_scanb<<<1, 64, 0, stream>>>(hist, base, cursor, NB);
  k_part<<<(E + 8191) / 8192, 512, 0, stream>>>(src, dst, cursor, bkt, E, NB);
  k_transpose<<<32, 256, 0, stream>>>(Wl1, Wr1, Wl2, Wr2, WlT, WrT, W2lT, W2rT);

  const int nb64 = (N + 63) / 64;
  k_aggb<<<NB, 512, 0, stream>>>(xb, bkt, base, agg, N);
  k_gemm1<<<nb64, 256, 0, stream>>>(x, agg, WlT, WrT, b1, h, N);
  k_gemm2<<<nb64, 256, 0, stream>>>(h, W2lT, y2, N);
  k_aggb<<<NB, 512, 0, stream>>>((const unsigned short*)y2, bkt, base, agg, N);
  k_final<<<nb64, 256, 0, stream>>>(h, agg, W2rT, b2, out, N);
}

// Round 4
// 1745.153 us; speedup vs baseline: 1.0235x; 1.0235x over previous
//
#include <hip/hip_runtime.h>
#include <hip/hip_bf16.h>
#include <stdint.h>

// FoodRiskGNN: 2-layer GraphSAGE (mean aggr), N=100000, E=1600000, 64->128->64.
// Bucketed (128 nodes/bucket) edge partition + fused LDS-accumulator
// aggregation with explicit 16-deep load batching (MLP) in the gather loop.

#define NBMAX 784

__device__ __forceinline__ float ldf(const float* p) { return *p; }
__device__ __forceinline__ float ldf(const __hip_bfloat16* p) { return __bfloat162float(*p); }

__device__ __forceinline__ unsigned short bf16u(float f) {
  __hip_bfloat16 h = __float2bfloat16(f);
  return *(unsigned short*)&h;
}

__device__ __forceinline__ void unpack8(uint4 v, float* a) {
  unsigned int u[4] = {v.x, v.y, v.z, v.w};
#pragma unroll
  for (int i = 0; i < 4; ++i) {
    a[2 * i]     = __uint_as_float(u[i] << 16);
    a[2 * i + 1] = __uint_as_float(u[i] & 0xffff0000u);
  }
}

// ---- x (f32) -> xb (bf16), 4 elems/thread ----
__global__ void k_cast(const float* __restrict__ x, unsigned short* __restrict__ xb, int n4) {
  int i = blockIdx.x * blockDim.x + threadIdx.x;
  if (i < n4) {
    float4 v = ((const float4*)x)[i];
    unsigned int u0 = (unsigned int)bf16u(v.x) | ((unsigned int)bf16u(v.y) << 16);
    unsigned int u1 = (unsigned int)bf16u(v.z) | ((unsigned int)bf16u(v.w) << 16);
    ((uint2*)xb)[i] = make_uint2(u0, u1);
  }
}

// ---- bucket histogram (LDS-staged) ----
__global__ __launch_bounds__(512) void k_bhist(const int* __restrict__ dst,
                                               unsigned int* __restrict__ hist, int E, int NB) {
  __shared__ unsigned int lh[NBMAX];
  const int tid = threadIdx.x;
  for (int b = tid; b < NB; b += 512) lh[b] = 0;
  __syncthreads();
  const int e0 = blockIdx.x * 16384;
  const int m = min(16384, E - e0);
  for (int i = tid; i < m; i += 512) atomicAdd(&lh[(unsigned int)dst[e0 + i] >> 7], 1u);
  __syncthreads();
  for (int b = tid; b < NB; b += 512) {
    unsigned int c = lh[b];
    if (c) atomicAdd(&hist[b], c);
  }
}

// ---- scan NB bucket counts -> base (exclusive) + cursor init. 1 wave. ----
__global__ void k_scanb(const unsigned int* __restrict__ hist, unsigned int* __restrict__ base,
                        unsigned int* __restrict__ cursor, int NB) {
  const int lane = threadIdx.x;
  unsigned int running = 0;
  for (int b0 = 0; b0 < NB; b0 += 64) {
    int i = b0 + lane;
    unsigned int v = (i < NB) ? hist[i] : 0;
    unsigned int s = v;
#pragma unroll
    for (int off = 1; off < 64; off <<= 1) {
      unsigned int t = __shfl_up(s, off);
      if (lane >= off) s += t;
    }
    if (i < NB) {
      base[i] = running + s - v;
      cursor[i] = running + s - v;
    }
    running += __shfl(s, 63);
  }
  if (lane == 0) base[NB] = running;
}

// ---- partition edges into bucket regions; payload = src | (dst&127)<<25 ----
__global__ __launch_bounds__(512) void k_part(const int* __restrict__ src,
                                              const int* __restrict__ dst,
                                              unsigned int* __restrict__ cursor,
                                              unsigned int* __restrict__ bkt, int E, int NB) {
  __shared__ unsigned int hist[NBMAX], lbase[NBMAX], gpos[NBMAX], lcur[NBMAX];
  __shared__ unsigned int stage[8192];
  __shared__ unsigned short stageb[8192];
  const int tid = threadIdx.x;
  const int e0 = blockIdx.x * 8192;
  const int m = min(8192, E - e0);
  for (int b = tid; b < NB; b += 512) { hist[b] = 0; lcur[b] = 0; }
  __syncthreads();
  for (int i = tid; i < m; i += 512) atomicAdd(&hist[(unsigned int)dst[e0 + i] >> 7], 1u);
  __syncthreads();
  if (tid < 64) {  // wave-0 exclusive scan of hist -> lbase
    unsigned int running = 0;
    for (int b0 = 0; b0 < NB; b0 += 64) {
      int i = b0 + tid;
      unsigned int v = (i < NB) ? hist[i] : 0;
      unsigned int s = v;
#pragma unroll
      for (int off = 1; off < 64; off <<= 1) {
        unsigned int t = __shfl_up(s, off);
        if (tid >= off) s += t;
      }
      if (i < NB) lbase[i] = running + s - v;
      running += __shfl(s, 63);
    }
  }
  __syncthreads();
  for (int b = tid; b < NB; b += 512) {
    unsigned int c = hist[b];
    gpos[b] = c ? atomicAdd(&cursor[b], c) : 0u;
  }
  for (int i = tid; i < m; i += 512) {
    int d = dst[e0 + i];
    int s = src[e0 + i];
    unsigned int b = (unsigned int)d >> 7;
    unsigned int p = lbase[b] + atomicAdd(&lcur[b], 1u);
    stage[p] = (unsigned int)s | ((unsigned int)(d & 127) << 25);
    stageb[p] = (unsigned short)b;
  }
  __syncthreads();
  for (int i = tid; i < m; i += 512) {
    unsigned int b = stageb[i];
    bkt[gpos[b] + (unsigned int)i - lbase[b]] = stage[i];
  }
}

// ---- bucketed mean-aggregation: block = 128-node bucket, LDS f32 acc.
//      Hot loop: 16 independent gather loads in flight per wave (MLP). ----
__global__ __launch_bounds__(512) void k_aggb(const unsigned short* __restrict__ feat,  // bf16[N][64]
                                              const unsigned int* __restrict__ bkt,
                                              const unsigned int* __restrict__ base,
                                              __hip_bfloat16* __restrict__ out, int N) {
  __shared__ float acc[128 * 64];      // 32 KB
  __shared__ unsigned int cnt[128];
  __shared__ unsigned int pbuf[2048];  // 8 KB
  const int tid = threadIdx.x;
  const int lane = tid & 63, w = tid >> 6;  // 8 waves
  const int nodelo = blockIdx.x << 7;
  const unsigned int* feat32 = (const unsigned int*)feat;
  for (int i = tid; i < 128 * 64; i += 512) acc[i] = 0.f;
  if (tid < 128) cnt[tid] = 0;
  const int ebeg = (int)base[blockIdx.x], eend = (int)base[blockIdx.x + 1];
  __syncthreads();
  const int half = lane >> 5, ch2 = lane & 31;
  for (int c0 = ebeg; c0 < eend; c0 += 2048) {
    const int m = min(2048, eend - c0);
    // stage packed edges + per-node degree count (coalesced, no divergence)
    for (int i = tid; i < m; i += 512) {
      unsigned int t = bkt[c0 + i];
      pbuf[i] = t;
      atomicAdd(&cnt[t >> 25], 1u);
    }
    __syncthreads();
    // wave w owns slots [w*256, w*256+256); half-wave per edge (2 edges/load-instr)
    const int wbase = w << 8;
    int mloc = m - wbase;
    mloc = (mloc < 0) ? 0 : (mloc > 256 ? 256 : mloc);
    const int nfull = mloc >> 5;  // groups of 32 edges (16 pairs)
    for (int g = 0; g < nfull; ++g) {
      const int sbase = wbase + (g << 5) + half;
      unsigned int e[16], v[16];
#pragma unroll
      for (int k = 0; k < 16; ++k) e[k] = pbuf[sbase + (k << 1)];
#pragma unroll
      for (int k = 0; k < 16; ++k)
        v[k] = feat32[((size_t)(e[k] & 0x1FFFFFFu) << 5) + ch2];  // 16 loads in flight
#pragma unroll
      for (int k = 0; k < 16; ++k) {
        const int dl = (int)(e[k] >> 25);
        float* ap = &acc[(dl << 6) + (ch2 << 1)];
        atomicAdd(ap,     __uint_as_float(v[k] << 16));
        atomicAdd(ap + 1, __uint_as_float(v[k] & 0xffff0000u));
      }
    }
    // tail (<32 edges for this wave)
    for (int s = wbase + (nfull << 5) + half; s < wbase + mloc; s += 2) {
      unsigned int e = pbuf[s];
      unsigned int v = feat32[((size_t)(e & 0x1FFFFFFu) << 5) + ch2];
      const int dl = (int)(e >> 25);
      float* ap = &acc[(dl << 6) + (ch2 << 1)];
      atomicAdd(ap,     __uint_as_float(v << 16));
      atomicAdd(ap + 1, __uint_as_float(v & 0xffff0000u));
    }
    __syncthreads();
  }
  unsigned int* o32 = (unsigned int*)out;
  for (int i = tid; i < 128 * 32; i += 512) {
    int r = i >> 5, c2 = i & 31;
    int node = nodelo + r;
    if (node < N) {
      unsigned int k = cnt[r];
      float sc = k ? 1.f / (float)k : 0.f;
      float a0 = acc[(r << 6) + (c2 << 1)] * sc;
      float a1 = acc[(r << 6) + (c2 << 1) + 1] * sc;
      o32[((size_t)node << 5) + c2] = (unsigned int)bf16u(a0) | ((unsigned int)bf16u(a1) << 16);
    }
  }
}

// ---- weight transposes ----
__global__ void k_transpose(const float* __restrict__ A, const float* __restrict__ B,
                            const float* __restrict__ C, const float* __restrict__ D,
                            float* __restrict__ AT, float* __restrict__ BT,
                            float* __restrict__ CT, float* __restrict__ DT) {
  int i = blockIdx.x * blockDim.x + threadIdx.x;
  if (i < 64 * 128) {
    int k = i >> 7, j = i & 127;  // A,B: [64][128]
    AT[j * 64 + k] = A[i];
    BT[j * 64 + k] = B[i];
    int k2 = i >> 6, j2 = i & 63;  // C,D: [128][64]
    CT[j2 * 128 + k2] = C[i];
    DT[j2 * 128 + k2] = D[i];
  }
}

// h = relu(agg1@Wl1 + x@Wr1 + b1). lane = node (64-node tile), wave owns 32 of 128 outputs.
__global__ __launch_bounds__(256) void k_gemm1(const float* __restrict__ x,
                                               const __hip_bfloat16* __restrict__ agg1,
                                               const float* __restrict__ WlT,
                                               const float* __restrict__ WrT,
                                               const float* __restrict__ b1,
                                               __hip_bfloat16* __restrict__ h, int n) {
  __shared__ __align__(16) __hip_bfloat16 sO[64][130];
  const int lane = threadIdx.x & 63;
  const int w = __builtin_amdgcn_readfirstlane((int)(threadIdx.x >> 6));
  const int n0 = blockIdx.x * 64;
  const int node = (n0 + lane < n) ? (n0 + lane) : (n - 1);

  float a[64], xr[64];
  {
    const uint4* pa = (const uint4*)(agg1 + (size_t)node * 64);
#pragma unroll
    for (int c = 0; c < 8; ++c) unpack8(pa[c], &a[c * 8]);
    const float4* px = (const float4*)(x + (size_t)node * 64);
#pragma unroll
    for (int c = 0; c < 16; ++c) {
      float4 v = px[c];
      xr[4 * c] = v.x; xr[4 * c + 1] = v.y; xr[4 * c + 2] = v.z; xr[4 * c + 3] = v.w;
    }
  }
  const int j0 = w * 32;
  for (int jj = 0; jj < 32; jj += 2) {
    const int j = j0 + jj;  // wave-uniform -> weight s_loads
    const float* wl0 = WlT + j * 64;
    const float* wr0 = WrT + j * 64;
    const float* wl1 = WlT + (j + 1) * 64;
    const float* wr1 = WrT + (j + 1) * 64;
    float acc0 = b1[j], acc1 = b1[j + 1];
#pragma unroll
    for (int k = 0; k < 64; ++k) {
      acc0 += a[k] * wl0[k] + xr[k] * wr0[k];
      acc1 += a[k] * wl1[k] + xr[k] * wr1[k];
    }
    sO[lane][j]     = __float2bfloat16(fmaxf(acc0, 0.f));
    sO[lane][j + 1] = __float2bfloat16(fmaxf(acc1, 0.f));
  }
  __syncthreads();
#pragma unroll
  for (int it = 0; it < 16; ++it) {
    int idx = it * 256 + threadIdx.x;
    int r = idx >> 6, c = idx & 63;
    int nn = n0 + r;
    if (nn < n)
      *(uint32_t*)((char*)(h + (size_t)nn * 128) + c * 4) =
          *(uint32_t*)((char*)&sO[r][0] + c * 4);
  }
}

// y2 = h@Wl2 (128->64). lane = node, wave owns 16 of 64 outputs.
__global__ __launch_bounds__(256) void k_gemm2(const __hip_bfloat16* __restrict__ h,
                                               const float* __restrict__ WT,
                                               __hip_bfloat16* __restrict__ y2, int n) {
  __shared__ __align__(16) __hip_bfloat16 sO[64][66];
  const int lane = threadIdx.x & 63;
  const int w = __builtin_amdgcn_readfirstlane((int)(threadIdx.x >> 6));
  const int n0 = blockIdx.x * 64;
  const int node = (n0 + lane < n) ? (n0 + lane) : (n - 1);

  float a[128];
  const uint4* p = (const uint4*)(h + (size_t)node * 128);
#pragma unroll
  for (int c = 0; c < 16; ++c) unpack8(p[c], &a[c * 8]);

  const int j0 = w * 16;
  for (int jj = 0; jj < 16; jj += 2) {
    int j = j0 + jj;
    const float* w0 = WT + j * 128;
    const float* w1 = WT + (j + 1) * 128;
    float acc0 = 0.f, acc1 = 0.f;
#pragma unroll
    for (int k = 0; k < 128; ++k) { acc0 += a[k] * w0[k]; acc1 += a[k] * w1[k]; }
    sO[lane][j]     = __float2bfloat16(acc0);
    sO[lane][j + 1] = __float2bfloat16(acc1);
  }
  __syncthreads();
#pragma unroll
  for (int it = 0; it < 8; ++it) {
    int idx = it * 256 + threadIdx.x;
    int r = idx >> 5, c = idx & 31;
    int nn = n0 + r;
    if (nn < n)
      *(uint32_t*)((char*)(y2 + (size_t)nn * 64) + c * 4) =
          *(uint32_t*)((char*)&sO[r][0] + c * 4);
  }
}

// out = sigmoid(agg2 + h@Wr2 + b2). lane = node, wave owns 16 of 64 outputs.
__global__ __launch_bounds__(256) void k_final(const __hip_bfloat16* __restrict__ h,
                                               const __hip_bfloat16* __restrict__ agg2,
                                               const float* __restrict__ WT,
                                               const float* __restrict__ b2,
                                               float* __restrict__ out, int n) {
  __shared__ float sO[64][65];
  const int lane = threadIdx.x & 63;
  const int w = __builtin_amdgcn_readfirstlane((int)(threadIdx.x >> 6));
  const int n0 = blockIdx.x * 64;
  const int node = (n0 + lane < n) ? (n0 + lane) : (n - 1);

  float a[128];
  const uint4* p = (const uint4*)(h + (size_t)node * 128);
#pragma unroll
  for (int c = 0; c < 16; ++c) unpack8(p[c], &a[c * 8]);

  const int j0 = w * 16;
  for (int jj = 0; jj < 16; jj += 2) {
    int j = j0 + jj;
    const float* w0 = WT + j * 128;
    const float* w1 = WT + (j + 1) * 128;
    float acc0 = b2[j] + ldf(agg2 + (size_t)node * 64 + j);
    float acc1 = b2[j + 1] + ldf(agg2 + (size_t)node * 64 + j + 1);
#pragma unroll
    for (int k = 0; k < 128; ++k) { acc0 += a[k] * w0[k]; acc1 += a[k] * w1[k]; }
    sO[lane][j]     = 1.f / (1.f + __expf(-acc0));
    sO[lane][j + 1] = 1.f / (1.f + __expf(-acc1));
  }
  __syncthreads();
#pragma unroll
  for (int it = 0; it < 16; ++it) {
    int idx = it * 256 + threadIdx.x;
    int r = idx >> 6, c = idx & 63;
    int nn = n0 + r;
    if (nn < n) out[(size_t)nn * 64 + c] = sO[r][c];
  }
}

extern "C" void kernel_launch(void* const* d_in, const int* in_sizes, int n_in,
                              void* d_out, int out_size, void* d_ws, size_t ws_size,
                              hipStream_t stream) {
  const float* x   = (const float*)d_in[0];
  const int*   ei  = (const int*)d_in[1];
  const float* Wl1 = (const float*)d_in[2];
  const float* Wr1 = (const float*)d_in[3];
  const float* b1  = (const float*)d_in[4];
  const float* Wl2 = (const float*)d_in[5];
  const float* Wr2 = (const float*)d_in[6];
  const float* b2  = (const float*)d_in[7];
  float* out = (float*)d_out;

  const int N = in_sizes[0] / 64;
  const int E = in_sizes[1] / 2;
  int NB = (N + 127) >> 7;  // 128 nodes per bucket
  if (NB > NBMAX) NB = NBMAX;
  const int* src = ei;
  const int* dst = ei + E;

  char* wp = (char*)d_ws;
  auto take = [&](size_t bytes) {
    char* p = wp;
    wp += (bytes + 255) & ~(size_t)255;
    return p;
  };
  unsigned int* hist   = (unsigned int*)take((size_t)NBMAX * 4);
  unsigned int* base   = (unsigned int*)take((size_t)(NBMAX + 1) * 4);
  unsigned int* cursor = (unsigned int*)take((size_t)NBMAX * 4);
  unsigned int* bkt    = (unsigned int*)take((size_t)E * 4);
  float* WlT  = (float*)take(64 * 128 * 4);
  float* WrT  = (float*)take(64 * 128 * 4);
  float* W2lT = (float*)take(128 * 64 * 4);
  float* W2rT = (float*)take(128 * 64 * 4);
  unsigned short* xb = (unsigned short*)take((size_t)N * 64 * 2);  // bf16 x; reused as y2
  __hip_bfloat16* agg = (__hip_bfloat16*)take((size_t)N * 64 * 2);
  __hip_bfloat16* h   = (__hip_bfloat16*)take((size_t)N * 128 * 2);
  __hip_bfloat16* y2  = (__hip_bfloat16*)xb;  // alias: xb dead after agg1

  hipMemsetAsync(hist, 0, (size_t)NBMAX * 4, stream);

  const int n4 = N * 16;  // N*64/4
  k_cast<<<(n4 + 255) / 256, 256, 0, stream>>>(x, xb, n4);
  k_bhist<<<(E + 16383) / 16384, 512, 0, stream>>>(dst, hist, E, NB);
  k_scanb<<<1, 64, 0, stream>>>(hist, base, cursor, NB);
  k_part<<<(E + 8191) / 8192, 512, 0, stream>>>(src, dst, cursor, bkt, E, NB);
  k_transpose<<<32, 256, 0, stream>>>(Wl1, Wr1, Wl2, Wr2, WlT, WrT, W2lT, W2rT);

  const int nb64 = (N + 63) / 64;
  k_aggb<<<NB, 512, 0, stream>>>(xb, bkt, base, agg, N);
  k_gemm1<<<nb64, 256, 0, stream>>>(x, agg, WlT, WrT, b1, h, N);
  k_gemm2<<<nb64, 256, 0, stream>>>(h, W2lT, y2, N);
  k_aggb<<<NB, 512, 0, stream>>>((const unsigned short*)y2, bkt, base, agg, N);
  k_final<<<nb64, 256, 0, stream>>>(h, agg, W2rT, b2, out, N);
}

// Round 5
// 475.176 us; speedup vs baseline: 3.7589x; 3.6726x over previous
//
#include <hip/hip_runtime.h>
#include <hip/hip_bf16.h>
#include <stdint.h>

// FoodRiskGNN: 2-layer GraphSAGE (mean aggr), N=100000, E=1600000, 64->128->64.
// Round-5: bucket partition (proven) + ATOMIC-FREE aggregation:
//   per bucket: LDS counting-sort edges by local dst (uint atomics only),
//   then wave-owns-16-nodes register accumulation with 8-deep gather MLP.

#define NBMAX 784
#define BCAP 3584  // max edges per 128-node bucket (mean 2048, sd 45; +34 sigma)

__device__ __forceinline__ float ldf(const float* p) { return *p; }
__device__ __forceinline__ float ldf(const __hip_bfloat16* p) { return __bfloat162float(*p); }

__device__ __forceinline__ float ldb(const unsigned short* p) {
  return __uint_as_float(((unsigned int)*p) << 16);
}

__device__ __forceinline__ unsigned short bf16u(float f) {
  __hip_bfloat16 h = __float2bfloat16(f);
  return *(unsigned short*)&h;
}

__device__ __forceinline__ void unpack8(uint4 v, float* a) {
  unsigned int u[4] = {v.x, v.y, v.z, v.w};
#pragma unroll
  for (int i = 0; i < 4; ++i) {
    a[2 * i]     = __uint_as_float(u[i] << 16);
    a[2 * i + 1] = __uint_as_float(u[i] & 0xffff0000u);
  }
}

// ---- x (f32) -> xb (bf16), 4 elems/thread ----
__global__ void k_cast(const float* __restrict__ x, unsigned short* __restrict__ xb, int n4) {
  int i = blockIdx.x * blockDim.x + threadIdx.x;
  if (i < n4) {
    float4 v = ((const float4*)x)[i];
    unsigned int u0 = (unsigned int)bf16u(v.x) | ((unsigned int)bf16u(v.y) << 16);
    unsigned int u1 = (unsigned int)bf16u(v.z) | ((unsigned int)bf16u(v.w) << 16);
    ((uint2*)xb)[i] = make_uint2(u0, u1);
  }
}

// ---- bucket histogram (LDS-staged) ----
__global__ __launch_bounds__(512) void k_bhist(const int* __restrict__ dst,
                                               unsigned int* __restrict__ hist, int E, int NB) {
  __shared__ unsigned int lh[NBMAX];
  const int tid = threadIdx.x;
  for (int b = tid; b < NB; b += 512) lh[b] = 0;
  __syncthreads();
  const int e0 = blockIdx.x * 16384;
  const int m = min(16384, E - e0);
  for (int i = tid; i < m; i += 512) atomicAdd(&lh[(unsigned int)dst[e0 + i] >> 7], 1u);
  __syncthreads();
  for (int b = tid; b < NB; b += 512) {
    unsigned int c = lh[b];
    if (c) atomicAdd(&hist[b], c);
  }
}

// ---- scan NB bucket counts -> base (exclusive) + cursor init. 1 wave. ----
__global__ void k_scanb(const unsigned int* __restrict__ hist, unsigned int* __restrict__ base,
                        unsigned int* __restrict__ cursor, int NB) {
  const int lane = threadIdx.x;
  unsigned int running = 0;
  for (int b0 = 0; b0 < NB; b0 += 64) {
    int i = b0 + lane;
    unsigned int v = (i < NB) ? hist[i] : 0;
    unsigned int s = v;
#pragma unroll
    for (int off = 1; off < 64; off <<= 1) {
      unsigned int t = __shfl_up(s, off);
      if (lane >= off) s += t;
    }
    if (i < NB) {
      base[i] = running + s - v;
      cursor[i] = running + s - v;
    }
    running += __shfl(s, 63);
  }
  if (lane == 0) base[NB] = running;
}

// ---- partition edges into bucket regions; payload = src | (dst&127)<<25 ----
__global__ __launch_bounds__(512) void k_part(const int* __restrict__ src,
                                              const int* __restrict__ dst,
                                              unsigned int* __restrict__ cursor,
                                              unsigned int* __restrict__ bkt, int E, int NB) {
  __shared__ unsigned int hist[NBMAX], lbase[NBMAX], gpos[NBMAX], lcur[NBMAX];
  __shared__ unsigned int stage[8192];
  __shared__ unsigned short stageb[8192];
  const int tid = threadIdx.x;
  const int e0 = blockIdx.x * 8192;
  const int m = min(8192, E - e0);
  for (int b = tid; b < NB; b += 512) { hist[b] = 0; lcur[b] = 0; }
  __syncthreads();
  for (int i = tid; i < m; i += 512) atomicAdd(&hist[(unsigned int)dst[e0 + i] >> 7], 1u);
  __syncthreads();
  if (tid < 64) {  // wave-0 exclusive scan of hist -> lbase
    unsigned int running = 0;
    for (int b0 = 0; b0 < NB; b0 += 64) {
      int i = b0 + tid;
      unsigned int v = (i < NB) ? hist[i] : 0;
      unsigned int s = v;
#pragma unroll
      for (int off = 1; off < 64; off <<= 1) {
        unsigned int t = __shfl_up(s, off);
        if (tid >= off) s += t;
      }
      if (i < NB) lbase[i] = running + s - v;
      running += __shfl(s, 63);
    }
  }
  __syncthreads();
  for (int b = tid; b < NB; b += 512) {
    unsigned int c = hist[b];
    gpos[b] = c ? atomicAdd(&cursor[b], c) : 0u;
  }
  for (int i = tid; i < m; i += 512) {
    int d = dst[e0 + i];
    int s = src[e0 + i];
    unsigned int b = (unsigned int)d >> 7;
    unsigned int p = lbase[b] + atomicAdd(&lcur[b], 1u);
    stage[p] = (unsigned int)s | ((unsigned int)(d & 127) << 25);
    stageb[p] = (unsigned short)b;
  }
  __syncthreads();
  for (int i = tid; i < m; i += 512) {
    unsigned int b = stageb[i];
    bkt[gpos[b] + (unsigned int)i - lbase[b]] = stage[i];
  }
}

// ---- atomic-free bucketed mean-aggregation ----
// Block = one 128-node bucket. Phase A: LDS counting-sort edges by local dst
// (uint atomics). Phase B: wave w owns nodes [16w,16w+16); lane = channel;
// register accumulation, 8-deep independent gather loads (scalar-base).
__global__ __launch_bounds__(512) void k_aggs(const unsigned short* __restrict__ feat,  // bf16[N][64]
                                              const unsigned int* __restrict__ bkt,
                                              const unsigned int* __restrict__ base,
                                              __hip_bfloat16* __restrict__ out, int N) {
  __shared__ unsigned int pbufA[BCAP];
  __shared__ unsigned int pbufB[BCAP];
  __shared__ unsigned int hist[128], lofs[128], cur[128];
  const int tid = threadIdx.x;
  const int lane = tid & 63;
  const int w = tid >> 6;  // 8 waves
  const int nodelo = blockIdx.x << 7;
  if (tid < 128) hist[tid] = 0;
  const int ebeg = (int)base[blockIdx.x];
  int m = (int)base[blockIdx.x + 1] - ebeg;
  m = (m > BCAP) ? BCAP : m;
  __syncthreads();
  // Phase A1: stage + local-dst histogram (uint LDS atomics)
  for (int i = tid; i < m; i += 512) {
    unsigned int t = bkt[ebeg + i];
    pbufA[i] = t;
    atomicAdd(&hist[t >> 25], 1u);
  }
  __syncthreads();
  // Phase A2: wave-0 exclusive scan of 128 counters
  if (tid < 64) {
    unsigned int v0 = hist[tid], v1 = hist[tid + 64];
    unsigned int s0 = v0, s1 = v1;
#pragma unroll
    for (int off = 1; off < 64; off <<= 1) {
      unsigned int t0 = __shfl_up(s0, off);
      unsigned int t1 = __shfl_up(s1, off);
      if (tid >= off) { s0 += t0; s1 += t1; }
    }
    unsigned int tot0 = __shfl(s0, 63);
    lofs[tid]      = s0 - v0;
    lofs[tid + 64] = tot0 + s1 - v1;
    cur[tid]       = s0 - v0;
    cur[tid + 64]  = tot0 + s1 - v1;
  }
  __syncthreads();
  // Phase A3: counting-sort scatter (uint LDS atomics)
  for (int i = tid; i < m; i += 512) {
    unsigned int t = pbufA[i];
    unsigned int p = atomicAdd(&cur[t >> 25], 1u);
    pbufB[p] = t;
  }
  __syncthreads();
  // Phase B: register accumulation, no atomics
  for (int q = 0; q < 16; ++q) {
    const int r = (w << 4) + q;           // local node, wave-uniform
    const unsigned int c = hist[r];
    const unsigned int o = lofs[r];
    float acc = 0.f;
    unsigned int e = 0;
    for (; e + 8 <= c; e += 8) {
      int s0 = __builtin_amdgcn_readfirstlane((int)(pbufB[o + e + 0] & 0x1FFFFFFu));
      int s1 = __builtin_amdgcn_readfirstlane((int)(pbufB[o + e + 1] & 0x1FFFFFFu));
      int s2 = __builtin_amdgcn_readfirstlane((int)(pbufB[o + e + 2] & 0x1FFFFFFu));
      int s3 = __builtin_amdgcn_readfirstlane((int)(pbufB[o + e + 3] & 0x1FFFFFFu));
      int s4 = __builtin_amdgcn_readfirstlane((int)(pbufB[o + e + 4] & 0x1FFFFFFu));
      int s5 = __builtin_amdgcn_readfirstlane((int)(pbufB[o + e + 5] & 0x1FFFFFFu));
      int s6 = __builtin_amdgcn_readfirstlane((int)(pbufB[o + e + 6] & 0x1FFFFFFu));
      int s7 = __builtin_amdgcn_readfirstlane((int)(pbufB[o + e + 7] & 0x1FFFFFFu));
      float f0 = ldb(feat + ((size_t)s0 << 6) + lane);
      float f1 = ldb(feat + ((size_t)s1 << 6) + lane);
      float f2 = ldb(feat + ((size_t)s2 << 6) + lane);
      float f3 = ldb(feat + ((size_t)s3 << 6) + lane);
      float f4 = ldb(feat + ((size_t)s4 << 6) + lane);
      float f5 = ldb(feat + ((size_t)s5 << 6) + lane);
      float f6 = ldb(feat + ((size_t)s6 << 6) + lane);
      float f7 = ldb(feat + ((size_t)s7 << 6) + lane);
      acc += f0 + f1 + f2 + f3 + f4 + f5 + f6 + f7;
    }
    for (; e + 4 <= c; e += 4) {
      int s0 = __builtin_amdgcn_readfirstlane((int)(pbufB[o + e + 0] & 0x1FFFFFFu));
      int s1 = __builtin_amdgcn_readfirstlane((int)(pbufB[o + e + 1] & 0x1FFFFFFu));
      int s2 = __builtin_amdgcn_readfirstlane((int)(pbufB[o + e + 2] & 0x1FFFFFFu));
      int s3 = __builtin_amdgcn_readfirstlane((int)(pbufB[o + e + 3] & 0x1FFFFFFu));
      float f0 = ldb(feat + ((size_t)s0 << 6) + lane);
      float f1 = ldb(feat + ((size_t)s1 << 6) + lane);
      float f2 = ldb(feat + ((size_t)s2 << 6) + lane);
      float f3 = ldb(feat + ((size_t)s3 << 6) + lane);
      acc += f0 + f1 + f2 + f3;
    }
    for (; e < c; ++e) {
      int s0 = __builtin_amdgcn_readfirstlane((int)(pbufB[o + e] & 0x1FFFFFFu));
      acc += ldb(feat + ((size_t)s0 << 6) + lane);
    }
    const int node = nodelo + r;
    if (node < N) {
      float sc = c ? (1.f / (float)c) : 0.f;
      unsigned short v = bf16u(acc * sc);
      ((unsigned short*)out)[((size_t)node << 6) + lane] = v;
    }
  }
}

// ---- weight transposes ----
__global__ void k_transpose(const float* __restrict__ A, const float* __restrict__ B,
                            const float* __restrict__ C, const float* __restrict__ D,
                            float* __restrict__ AT, float* __restrict__ BT,
                            float* __restrict__ CT, float* __restrict__ DT) {
  int i = blockIdx.x * blockDim.x + threadIdx.x;
  if (i < 64 * 128) {
    int k = i >> 7, j = i & 127;  // A,B: [64][128]
    AT[j * 64 + k] = A[i];
    BT[j * 64 + k] = B[i];
    int k2 = i >> 6, j2 = i & 63;  // C,D: [128][64]
    CT[j2 * 128 + k2] = C[i];
    DT[j2 * 128 + k2] = D[i];
  }
}

// h = relu(agg1@Wl1 + x@Wr1 + b1). lane = node (64-node tile), wave owns 32 of 128 outputs.
__global__ __launch_bounds__(256) void k_gemm1(const float* __restrict__ x,
                                               const __hip_bfloat16* __restrict__ agg1,
                                               const float* __restrict__ WlT,
                                               const float* __restrict__ WrT,
                                               const float* __restrict__ b1,
                                               __hip_bfloat16* __restrict__ h, int n) {
  __shared__ __align__(16) __hip_bfloat16 sO[64][130];
  const int lane = threadIdx.x & 63;
  const int w = __builtin_amdgcn_readfirstlane((int)(threadIdx.x >> 6));
  const int n0 = blockIdx.x * 64;
  const int node = (n0 + lane < n) ? (n0 + lane) : (n - 1);

  float a[64], xr[64];
  {
    const uint4* pa = (const uint4*)(agg1 + (size_t)node * 64);
#pragma unroll
    for (int c = 0; c < 8; ++c) unpack8(pa[c], &a[c * 8]);
    const float4* px = (const float4*)(x + (size_t)node * 64);
#pragma unroll
    for (int c = 0; c < 16; ++c) {
      float4 v = px[c];
      xr[4 * c] = v.x; xr[4 * c + 1] = v.y; xr[4 * c + 2] = v.z; xr[4 * c + 3] = v.w;
    }
  }
  const int j0 = w * 32;
  for (int jj = 0; jj < 32; jj += 2) {
    const int j = j0 + jj;  // wave-uniform -> weight s_loads
    const float* wl0 = WlT + j * 64;
    const float* wr0 = WrT + j * 64;
    const float* wl1 = WlT + (j + 1) * 64;
    const float* wr1 = WrT + (j + 1) * 64;
    float acc0 = b1[j], acc1 = b1[j + 1];
#pragma unroll
    for (int k = 0; k < 64; ++k) {
      acc0 += a[k] * wl0[k] + xr[k] * wr0[k];
      acc1 += a[k] * wl1[k] + xr[k] * wr1[k];
    }
    sO[lane][j]     = __float2bfloat16(fmaxf(acc0, 0.f));
    sO[lane][j + 1] = __float2bfloat16(fmaxf(acc1, 0.f));
  }
  __syncthreads();
#pragma unroll
  for (int it = 0; it < 16; ++it) {
    int idx = it * 256 + threadIdx.x;
    int r = idx >> 6, c = idx & 63;
    int nn = n0 + r;
    if (nn < n)
      *(uint32_t*)((char*)(h + (size_t)nn * 128) + c * 4) =
          *(uint32_t*)((char*)&sO[r][0] + c * 4);
  }
}

// y2 = h@Wl2 (128->64). lane = node, wave owns 16 of 64 outputs.
__global__ __launch_bounds__(256) void k_gemm2(const __hip_bfloat16* __restrict__ h,
                                               const float* __restrict__ WT,
                                               __hip_bfloat16* __restrict__ y2, int n) {
  __shared__ __align__(16) __hip_bfloat16 sO[64][66];
  const int lane = threadIdx.x & 63;
  const int w = __builtin_amdgcn_readfirstlane((int)(threadIdx.x >> 6));
  const int n0 = blockIdx.x * 64;
  const int node = (n0 + lane < n) ? (n0 + lane) : (n - 1);

  float a[128];
  const uint4* p = (const uint4*)(h + (size_t)node * 128);
#pragma unroll
  for (int c = 0; c < 16; ++c) unpack8(p[c], &a[c * 8]);

  const int j0 = w * 16;
  for (int jj = 0; jj < 16; jj += 2) {
    int j = j0 + jj;
    const float* w0 = WT + j * 128;
    const float* w1 = WT + (j + 1) * 128;
    float acc0 = 0.f, acc1 = 0.f;
#pragma unroll
    for (int k = 0; k < 128; ++k) { acc0 += a[k] * w0[k]; acc1 += a[k] * w1[k]; }
    sO[lane][j]     = __float2bfloat16(acc0);
    sO[lane][j + 1] = __float2bfloat16(acc1);
  }
  __syncthreads();
#pragma unroll
  for (int it = 0; it < 8; ++it) {
    int idx = it * 256 + threadIdx.x;
    int r = idx >> 5, c = idx & 31;
    int nn = n0 + r;
    if (nn < n)
      *(uint32_t*)((char*)(y2 + (size_t)nn * 64) + c * 4) =
          *(uint32_t*)((char*)&sO[r][0] + c * 4);
  }
}

// out = sigmoid(agg2 + h@Wr2 + b2). lane = node, wave owns 16 of 64 outputs.
__global__ __launch_bounds__(256) void k_final(const __hip_bfloat16* __restrict__ h,
                                               const __hip_bfloat16* __restrict__ agg2,
                                               const float* __restrict__ WT,
                                               const float* __restrict__ b2,
                                               float* __restrict__ out, int n) {
  __shared__ float sO[64][65];
  const int lane = threadIdx.x & 63;
  const int w = __builtin_amdgcn_readfirstlane((int)(threadIdx.x >> 6));
  const int n0 = blockIdx.x * 64;
  const int node = (n0 + lane < n) ? (n0 + lane) : (n - 1);

  float a[128];
  const uint4* p = (const uint4*)(h + (size_t)node * 128);
#pragma unroll
  for (int c = 0; c < 16; ++c) unpack8(p[c], &a[c * 8]);

  const int j0 = w * 16;
  for (int jj = 0; jj < 16; jj += 2) {
    int j = j0 + jj;
    const float* w0 = WT + j * 128;
    const float* w1 = WT + (j + 1) * 128;
    float acc0 = b2[j] + ldf(agg2 + (size_t)node * 64 + j);
    float acc1 = b2[j + 1] + ldf(agg2 + (size_t)node * 64 + j + 1);
#pragma unroll
    for (int k = 0; k < 128; ++k) { acc0 += a[k] * w0[k]; acc1 += a[k] * w1[k]; }
    sO[lane][j]     = 1.f / (1.f + __expf(-acc0));
    sO[lane][j + 1] = 1.f / (1.f + __expf(-acc1));
  }
  __syncthreads();
#pragma unroll
  for (int it = 0; it < 16; ++it) {
    int idx = it * 256 + threadIdx.x;
    int r = idx >> 6, c = idx & 63;
    int nn = n0 + r;
    if (nn < n) out[(size_t)nn * 64 + c] = sO[r][c];
  }
}

extern "C" void kernel_launch(void* const* d_in, const int* in_sizes, int n_in,
                              void* d_out, int out_size, void* d_ws, size_t ws_size,
                              hipStream_t stream) {
  const float* x   = (const float*)d_in[0];
  const int*   ei  = (const int*)d_in[1];
  const float* Wl1 = (const float*)d_in[2];
  const float* Wr1 = (const float*)d_in[3];
  const float* b1  = (const float*)d_in[4];
  const float* Wl2 = (const float*)d_in[5];
  const float* Wr2 = (const float*)d_in[6];
  const float* b2  = (const float*)d_in[7];
  float* out = (float*)d_out;

  const int N = in_sizes[0] / 64;
  const int E = in_sizes[1] / 2;
  int NB = (N + 127) >> 7;  // 128 nodes per bucket
  if (NB > NBMAX) NB = NBMAX;
  const int* src = ei;
  const int* dst = ei + E;

  char* wp = (char*)d_ws;
  auto take = [&](size_t bytes) {
    char* p = wp;
    wp += (bytes + 255) & ~(size_t)255;
    return p;
  };
  unsigned int* hist   = (unsigned int*)take((size_t)NBMAX * 4);
  unsigned int* base   = (unsigned int*)take((size_t)(NBMAX + 1) * 4);
  unsigned int* cursor = (unsigned int*)take((size_t)NBMAX * 4);
  unsigned int* bkt    = (unsigned int*)take((size_t)E * 4);
  float* WlT  = (float*)take(64 * 128 * 4);
  float* WrT  = (float*)take(64 * 128 * 4);
  float* W2lT = (float*)take(128 * 64 * 4);
  float* W2rT = (float*)take(128 * 64 * 4);
  unsigned short* xb = (unsigned short*)take((size_t)N * 64 * 2);  // bf16 x; reused as y2
  __hip_bfloat16* agg = (__hip_bfloat16*)take((size_t)N * 64 * 2);
  __hip_bfloat16* h   = (__hip_bfloat16*)take((size_t)N * 128 * 2);
  __hip_bfloat16* y2  = (__hip_bfloat16*)xb;  // alias: xb dead after agg1

  hipMemsetAsync(hist, 0, (size_t)NBMAX * 4, stream);

  const int n4 = N * 16;  // N*64/4
  k_cast<<<(n4 + 255) / 256, 256, 0, stream>>>(x, xb, n4);
  k_bhist<<<(E + 16383) / 16384, 512, 0, stream>>>(dst, hist, E, NB);
  k_scanb<<<1, 64, 0, stream>>>(hist, base, cursor, NB);
  k_part<<<(E + 8191) / 8192, 512, 0, stream>>>(src, dst, cursor, bkt, E, NB);
  k_transpose<<<32, 256, 0, stream>>>(Wl1, Wr1, Wl2, Wr2, WlT, WrT, W2lT, W2rT);

  const int nb64 = (N + 63) / 64;
  k_aggs<<<NB, 512, 0, stream>>>(xb, bkt, base, agg, N);
  k_gemm1<<<nb64, 256, 0, stream>>>(x, agg, WlT, WrT, b1, h, N);
  k_gemm2<<<nb64, 256, 0, stream>>>(h, W2lT, y2, N);
  k_aggs<<<NB, 512, 0, stream>>>((const unsigned short*)y2, bkt, base, agg, N);
  k_final<<<nb64, 256, 0, stream>>>(h, agg, W2rT, b2, out, N);
}

// Round 6
// 251.288 us; speedup vs baseline: 7.1079x; 1.8910x over previous
//
#include <hip/hip_runtime.h>
#include <hip/hip_bf16.h>
#include <stdint.h>

// FoodRiskGNN: 2-layer GraphSAGE (mean aggr), N=100000, E=1600000, 64->128->64.
// Round-6: MFMA (bf16) GEMMs + fused layer-2.
//   cast x->xb (bf16); bucket partition (proven, unchanged); wprep packs
//   [Wl1;Wr1] and [Wl2|Wr2] into MFMA B-fragment order (bf16).
//   agg1 = mean-gather(xb)                       [k_aggs, unchanged]
//   h    = relu([agg1|xb] @ W1cat + b1)          [k_mm1, MFMA 16x16x32]
//   [y2|z2] = h @ [Wl2|Wr2]                      [k_mm2, MFMA; y2 bf16, z2 f32]
//   agg2 = mean-gather(y2)                       [k_aggs]
//   out  = sigmoid(agg2 + z2 + b2)               [k_sig elementwise]

#define NBMAX 784
#define BCAP 3584  // max edges per 128-node bucket (mean 2048, sd 45; +34 sigma)

typedef __bf16 bf16x8 __attribute__((ext_vector_type(8)));
typedef float f32x4 __attribute__((ext_vector_type(4)));

__device__ __forceinline__ float ldb(const unsigned short* p) {
  return __uint_as_float(((unsigned int)*p) << 16);
}

__device__ __forceinline__ unsigned short bf16u(float f) {
  __hip_bfloat16 h = __float2bfloat16(f);
  return *(unsigned short*)&h;
}

// ---- x (f32) -> xb (bf16), 4 elems/thread ----
__global__ void k_cast(const float* __restrict__ x, unsigned short* __restrict__ xb, int n4) {
  int i = blockIdx.x * blockDim.x + threadIdx.x;
  if (i < n4) {
    float4 v = ((const float4*)x)[i];
    unsigned int u0 = (unsigned int)bf16u(v.x) | ((unsigned int)bf16u(v.y) << 16);
    unsigned int u1 = (unsigned int)bf16u(v.z) | ((unsigned int)bf16u(v.w) << 16);
    ((uint2*)xb)[i] = make_uint2(u0, u1);
  }
}

// ---- bucket histogram (LDS-staged) ----
__global__ __launch_bounds__(512) void k_bhist(const int* __restrict__ dst,
                                               unsigned int* __restrict__ hist, int E, int NB) {
  __shared__ unsigned int lh[NBMAX];
  const int tid = threadIdx.x;
  for (int b = tid; b < NB; b += 512) lh[b] = 0;
  __syncthreads();
  const int e0 = blockIdx.x * 16384;
  const int m = min(16384, E - e0);
  for (int i = tid; i < m; i += 512) atomicAdd(&lh[(unsigned int)dst[e0 + i] >> 7], 1u);
  __syncthreads();
  for (int b = tid; b < NB; b += 512) {
    unsigned int c = lh[b];
    if (c) atomicAdd(&hist[b], c);
  }
}

// ---- scan NB bucket counts -> base (exclusive) + cursor init. 1 wave. ----
__global__ void k_scanb(const unsigned int* __restrict__ hist, unsigned int* __restrict__ base,
                        unsigned int* __restrict__ cursor, int NB) {
  const int lane = threadIdx.x;
  unsigned int running = 0;
  for (int b0 = 0; b0 < NB; b0 += 64) {
    int i = b0 + lane;
    unsigned int v = (i < NB) ? hist[i] : 0;
    unsigned int s = v;
#pragma unroll
    for (int off = 1; off < 64; off <<= 1) {
      unsigned int t = __shfl_up(s, off);
      if (lane >= off) s += t;
    }
    if (i < NB) {
      base[i] = running + s - v;
      cursor[i] = running + s - v;
    }
    running += __shfl(s, 63);
  }
  if (lane == 0) base[NB] = running;
}

// ---- partition edges into bucket regions; payload = src | (dst&127)<<25 ----
__global__ __launch_bounds__(512) void k_part(const int* __restrict__ src,
                                              const int* __restrict__ dst,
                                              unsigned int* __restrict__ cursor,
                                              unsigned int* __restrict__ bkt, int E, int NB) {
  __shared__ unsigned int hist[NBMAX], lbase[NBMAX], gpos[NBMAX], lcur[NBMAX];
  __shared__ unsigned int stage[8192];
  __shared__ unsigned short stageb[8192];
  const int tid = threadIdx.x;
  const int e0 = blockIdx.x * 8192;
  const int m = min(8192, E - e0);
  for (int b = tid; b < NB; b += 512) { hist[b] = 0; lcur[b] = 0; }
  __syncthreads();
  for (int i = tid; i < m; i += 512) atomicAdd(&hist[(unsigned int)dst[e0 + i] >> 7], 1u);
  __syncthreads();
  if (tid < 64) {  // wave-0 exclusive scan of hist -> lbase
    unsigned int running = 0;
    for (int b0 = 0; b0 < NB; b0 += 64) {
      int i = b0 + tid;
      unsigned int v = (i < NB) ? hist[i] : 0;
      unsigned int s = v;
#pragma unroll
      for (int off = 1; off < 64; off <<= 1) {
        unsigned int t = __shfl_up(s, off);
        if (tid >= off) s += t;
      }
      if (i < NB) lbase[i] = running + s - v;
      running += __shfl(s, 63);
    }
  }
  __syncthreads();
  for (int b = tid; b < NB; b += 512) {
    unsigned int c = hist[b];
    gpos[b] = c ? atomicAdd(&cursor[b], c) : 0u;
  }
  for (int i = tid; i < m; i += 512) {
    int d = dst[e0 + i];
    int s = src[e0 + i];
    unsigned int b = (unsigned int)d >> 7;
    unsigned int p = lbase[b] + atomicAdd(&lcur[b], 1u);
    stage[p] = (unsigned int)s | ((unsigned int)(d & 127) << 25);
    stageb[p] = (unsigned short)b;
  }
  __syncthreads();
  for (int i = tid; i < m; i += 512) {
    unsigned int b = stageb[i];
    bkt[gpos[b] + (unsigned int)i - lbase[b]] = stage[i];
  }
}

// ---- atomic-free bucketed mean-aggregation (round-5 proven) ----
__global__ __launch_bounds__(512) void k_aggs(const unsigned short* __restrict__ feat,  // bf16[N][64]
                                              const unsigned int* __restrict__ bkt,
                                              const unsigned int* __restrict__ base,
                                              unsigned short* __restrict__ out, int N) {
  __shared__ unsigned int pbufA[BCAP];
  __shared__ unsigned int pbufB[BCAP];
  __shared__ unsigned int hist[128], lofs[128], cur[128];
  const int tid = threadIdx.x;
  const int lane = tid & 63;
  const int w = tid >> 6;  // 8 waves
  const int nodelo = blockIdx.x << 7;
  if (tid < 128) hist[tid] = 0;
  const int ebeg = (int)base[blockIdx.x];
  int m = (int)base[blockIdx.x + 1] - ebeg;
  m = (m > BCAP) ? BCAP : m;
  __syncthreads();
  for (int i = tid; i < m; i += 512) {
    unsigned int t = bkt[ebeg + i];
    pbufA[i] = t;
    atomicAdd(&hist[t >> 25], 1u);
  }
  __syncthreads();
  if (tid < 64) {
    unsigned int v0 = hist[tid], v1 = hist[tid + 64];
    unsigned int s0 = v0, s1 = v1;
#pragma unroll
    for (int off = 1; off < 64; off <<= 1) {
      unsigned int t0 = __shfl_up(s0, off);
      unsigned int t1 = __shfl_up(s1, off);
      if (tid >= off) { s0 += t0; s1 += t1; }
    }
    unsigned int tot0 = __shfl(s0, 63);
    lofs[tid]      = s0 - v0;
    lofs[tid + 64] = tot0 + s1 - v1;
    cur[tid]       = s0 - v0;
    cur[tid + 64]  = tot0 + s1 - v1;
  }
  __syncthreads();
  for (int i = tid; i < m; i += 512) {
    unsigned int t = pbufA[i];
    unsigned int p = atomicAdd(&cur[t >> 25], 1u);
    pbufB[p] = t;
  }
  __syncthreads();
  for (int q = 0; q < 16; ++q) {
    const int r = (w << 4) + q;           // local node, wave-uniform
    const unsigned int c = hist[r];
    const unsigned int o = lofs[r];
    float acc = 0.f;
    unsigned int e = 0;
    for (; e + 8 <= c; e += 8) {
      int s0 = __builtin_amdgcn_readfirstlane((int)(pbufB[o + e + 0] & 0x1FFFFFFu));
      int s1 = __builtin_amdgcn_readfirstlane((int)(pbufB[o + e + 1] & 0x1FFFFFFu));
      int s2 = __builtin_amdgcn_readfirstlane((int)(pbufB[o + e + 2] & 0x1FFFFFFu));
      int s3 = __builtin_amdgcn_readfirstlane((int)(pbufB[o + e + 3] & 0x1FFFFFFu));
      int s4 = __builtin_amdgcn_readfirstlane((int)(pbufB[o + e + 4] & 0x1FFFFFFu));
      int s5 = __builtin_amdgcn_readfirstlane((int)(pbufB[o + e + 5] & 0x1FFFFFFu));
      int s6 = __builtin_amdgcn_readfirstlane((int)(pbufB[o + e + 6] & 0x1FFFFFFu));
      int s7 = __builtin_amdgcn_readfirstlane((int)(pbufB[o + e + 7] & 0x1FFFFFFu));
      float f0 = ldb(feat + ((size_t)s0 << 6) + lane);
      float f1 = ldb(feat + ((size_t)s1 << 6) + lane);
      float f2 = ldb(feat + ((size_t)s2 << 6) + lane);
      float f3 = ldb(feat + ((size_t)s3 << 6) + lane);
      float f4 = ldb(feat + ((size_t)s4 << 6) + lane);
      float f5 = ldb(feat + ((size_t)s5 << 6) + lane);
      float f6 = ldb(feat + ((size_t)s6 << 6) + lane);
      float f7 = ldb(feat + ((size_t)s7 << 6) + lane);
      acc += f0 + f1 + f2 + f3 + f4 + f5 + f6 + f7;
    }
    for (; e + 4 <= c; e += 4) {
      int s0 = __builtin_amdgcn_readfirstlane((int)(pbufB[o + e + 0] & 0x1FFFFFFu));
      int s1 = __builtin_amdgcn_readfirstlane((int)(pbufB[o + e + 1] & 0x1FFFFFFu));
      int s2 = __builtin_amdgcn_readfirstlane((int)(pbufB[o + e + 2] & 0x1FFFFFFu));
      int s3 = __builtin_amdgcn_readfirstlane((int)(pbufB[o + e + 3] & 0x1FFFFFFu));
      float f0 = ldb(feat + ((size_t)s0 << 6) + lane);
      float f1 = ldb(feat + ((size_t)s1 << 6) + lane);
      float f2 = ldb(feat + ((size_t)s2 << 6) + lane);
      float f3 = ldb(feat + ((size_t)s3 << 6) + lane);
      acc += f0 + f1 + f2 + f3;
    }
    for (; e < c; ++e) {
      int s0 = __builtin_amdgcn_readfirstlane((int)(pbufB[o + e] & 0x1FFFFFFu));
      acc += ldb(feat + ((size_t)s0 << 6) + lane);
    }
    const int node = nodelo + r;
    if (node < N) {
      float sc = c ? (1.f / (float)c) : 0.f;
      out[((size_t)node << 6) + lane] = bf16u(acc * sc);
    }
  }
}

// ---- pack weights into MFMA B-fragment order (bf16) ----
// B-frag layout for mfma_f32_16x16x32_bf16: lane holds B[k=(lane>>4)*8+i][col=lane&15].
// W1p: [nt=8][kb=4][lane=64] fragments of [Wl1;Wr1] (K=128, cols=128)
// W2p: same for [Wl2|Wr2] (K=128; cols 0..63 = Wl2, 64..127 = Wr2)
__global__ void k_wprep(const float* __restrict__ Wl1, const float* __restrict__ Wr1,  // [64][128]
                        const float* __restrict__ Wl2, const float* __restrict__ Wr2,  // [128][64]
                        unsigned short* __restrict__ W1p, unsigned short* __restrict__ W2p) {
  int f = blockIdx.x * blockDim.x + threadIdx.x;  // 0..4095
  if (f >= 4096) return;
  int mat = f >> 11;
  int fr = f & 2047;             // (nt*4+kb)*64 + lane
  int lane = fr & 63;
  int ntkb = fr >> 6;
  int nt = ntkb >> 2, kb = ntkb & 3;
  int col = (nt << 4) + (lane & 15);
  int k0 = (kb << 5) + ((lane >> 4) << 3);
  unsigned short v[8];
#pragma unroll
  for (int i = 0; i < 8; ++i) {
    int k = k0 + i;
    float val;
    if (mat == 0) val = (k < 64) ? Wl1[k * 128 + col] : Wr1[(k - 64) * 128 + col];
    else          val = (col < 64) ? Wl2[k * 64 + col] : Wr2[k * 64 + (col - 64)];
    v[i] = bf16u(val);
  }
  *(uint4*)((mat ? W2p : W1p) + (size_t)fr * 8) = *(const uint4*)v;
}

// ---- h = relu([agg|xb] @ W1cat + b1), MFMA. Block = 64 nodes, 4 waves x 16. ----
__global__ __launch_bounds__(256) void k_mm1(const unsigned short* __restrict__ agg,
                                             const unsigned short* __restrict__ xb,
                                             const unsigned short* __restrict__ W1p,
                                             const float* __restrict__ b1,
                                             unsigned short* __restrict__ h, int N) {
  __shared__ __align__(16) unsigned short sO[64][136];  // 128 + pad(8) -> 272B rows
  const int tid = threadIdx.x;
  const int lane = tid & 63;
  const int w = tid >> 6;
  const int n0 = blockIdx.x << 6;
  const int row16 = lane & 15;
  const int kgrp = lane >> 4;  // 0..3
  int node = n0 + (w << 4) + row16;
  if (node >= N) node = N - 1;

  bf16x8 a[4];  // A-frag: row=lane&15, k = kb*32 + kgrp*8 + i
  {
    const unsigned short* ra = agg + ((size_t)node << 6);
    const unsigned short* rx = xb + ((size_t)node << 6);
    a[0] = *(const bf16x8*)(ra + kgrp * 8);
    a[1] = *(const bf16x8*)(ra + 32 + kgrp * 8);
    a[2] = *(const bf16x8*)(rx + kgrp * 8);
    a[3] = *(const bf16x8*)(rx + 32 + kgrp * 8);
  }
  const bf16x8* Wp = (const bf16x8*)W1p;
#pragma unroll
  for (int nt = 0; nt < 8; ++nt) {
    f32x4 acc = {0.f, 0.f, 0.f, 0.f};
#pragma unroll
    for (int kb = 0; kb < 4; ++kb) {
      bf16x8 b = Wp[(nt * 4 + kb) * 64 + lane];
      acc = __builtin_amdgcn_mfma_f32_16x16x32_bf16(a[kb], b, acc, 0, 0, 0);
    }
    const int col = (nt << 4) + row16;  // C/D: col = lane&15
    const float bias = b1[col];
#pragma unroll
    for (int r = 0; r < 4; ++r) {       // C/D: row = kgrp*4 + r
      int lrow = (w << 4) + (kgrp << 2) + r;
      sO[lrow][col] = bf16u(fmaxf(acc[r] + bias, 0.f));
    }
  }
  __syncthreads();
  // 64 rows x 128 bf16 = 1024 x 16B chunks
#pragma unroll
  for (int it = 0; it < 4; ++it) {
    int idx = it * 256 + tid;
    int r = idx >> 4, sub = idx & 15;
    int nn = n0 + r;
    if (nn < N)
      *(uint4*)((char*)(h + ((size_t)nn << 7)) + sub * 16) =
          *(const uint4*)((char*)&sO[r][0] + sub * 16);
  }
}

// ---- [y2|z2] = h @ [Wl2|Wr2], MFMA. y2 bf16 [N][64], z2 f32 [N][64]. ----
__global__ __launch_bounds__(256) void k_mm2(const unsigned short* __restrict__ h,
                                             const unsigned short* __restrict__ W2p,
                                             unsigned short* __restrict__ y2,
                                             float* __restrict__ z2, int N) {
  __shared__ __align__(16) unsigned short sY[64][72];  // 144B rows
  __shared__ __align__(16) float sZ[64][68];           // 272B rows
  const int tid = threadIdx.x;
  const int lane = tid & 63;
  const int w = tid >> 6;
  const int n0 = blockIdx.x << 6;
  const int row16 = lane & 15;
  const int kgrp = lane >> 4;
  int node = n0 + (w << 4) + row16;
  if (node >= N) node = N - 1;

  bf16x8 a[4];
  {
    const unsigned short* rh = h + ((size_t)node << 7);
    a[0] = *(const bf16x8*)(rh + kgrp * 8);
    a[1] = *(const bf16x8*)(rh + 32 + kgrp * 8);
    a[2] = *(const bf16x8*)(rh + 64 + kgrp * 8);
    a[3] = *(const bf16x8*)(rh + 96 + kgrp * 8);
  }
  const bf16x8* Wp = (const bf16x8*)W2p;
#pragma unroll
  for (int nt = 0; nt < 8; ++nt) {
    f32x4 acc = {0.f, 0.f, 0.f, 0.f};
#pragma unroll
    for (int kb = 0; kb < 4; ++kb) {
      bf16x8 b = Wp[(nt * 4 + kb) * 64 + lane];
      acc = __builtin_amdgcn_mfma_f32_16x16x32_bf16(a[kb], b, acc, 0, 0, 0);
    }
    const int col = (nt << 4) + row16;
#pragma unroll
    for (int r = 0; r < 4; ++r) {
      int lrow = (w << 4) + (kgrp << 2) + r;
      if (nt < 4) sY[lrow][col] = bf16u(acc[r]);
      else        sZ[lrow][col - 64] = acc[r];
    }
  }
  __syncthreads();
  // y2: 64 rows x 64 bf16 = 512 x 16B
#pragma unroll
  for (int it = 0; it < 2; ++it) {
    int idx = it * 256 + tid;
    int r = idx >> 3, sub = idx & 7;
    int nn = n0 + r;
    if (nn < N)
      *(uint4*)((char*)(y2 + ((size_t)nn << 6)) + sub * 16) =
          *(const uint4*)((char*)&sY[r][0] + sub * 16);
  }
  // z2: 64 rows x 64 f32 = 1024 x 16B
#pragma unroll
  for (int it = 0; it < 4; ++it) {
    int idx = it * 256 + tid;
    int r = idx >> 4, sub = idx & 15;
    int nn = n0 + r;
    if (nn < N)
      *(uint4*)((char*)(z2 + ((size_t)nn << 6)) + sub * 16) =
          *(const uint4*)((char*)&sZ[r][0] + sub * 16);
  }
}

// ---- out = sigmoid(agg2 + z2 + b2), elementwise; thread = 4 channels ----
__global__ void k_sig(const unsigned short* __restrict__ agg2, const float* __restrict__ z2,
                      const float* __restrict__ b2, float* __restrict__ out, int n16) {
  int i = blockIdx.x * blockDim.x + threadIdx.x;
  if (i < n16) {
    int c4 = (i & 15) << 2;
    uint2 av = *(const uint2*)(agg2 + ((size_t)(i >> 4) << 6) + c4);
    float4 zv = *(const float4*)(z2 + ((size_t)(i >> 4) << 6) + c4);
    float a0 = __uint_as_float(av.x << 16);
    float a1 = __uint_as_float(av.x & 0xffff0000u);
    float a2 = __uint_as_float(av.y << 16);
    float a3 = __uint_as_float(av.y & 0xffff0000u);
    float4 o;
    o.x = 1.f / (1.f + __expf(-(a0 + zv.x + b2[c4])));
    o.y = 1.f / (1.f + __expf(-(a1 + zv.y + b2[c4 + 1])));
    o.z = 1.f / (1.f + __expf(-(a2 + zv.z + b2[c4 + 2])));
    o.w = 1.f / (1.f + __expf(-(a3 + zv.w + b2[c4 + 3])));
    *(float4*)(out + ((size_t)(i >> 4) << 6) + c4) = o;
  }
}

extern "C" void kernel_launch(void* const* d_in, const int* in_sizes, int n_in,
                              void* d_out, int out_size, void* d_ws, size_t ws_size,
                              hipStream_t stream) {
  const float* x   = (const float*)d_in[0];
  const int*   ei  = (const int*)d_in[1];
  const float* Wl1 = (const float*)d_in[2];
  const float* Wr1 = (const float*)d_in[3];
  const float* b1  = (const float*)d_in[4];
  const float* Wl2 = (const float*)d_in[5];
  const float* Wr2 = (const float*)d_in[6];
  const float* b2  = (const float*)d_in[7];
  float* out = (float*)d_out;

  const int N = in_sizes[0] / 64;
  const int E = in_sizes[1] / 2;
  int NB = (N + 127) >> 7;
  if (NB > NBMAX) NB = NBMAX;
  const int* src = ei;
  const int* dst = ei + E;

  char* wp = (char*)d_ws;
  auto take = [&](size_t bytes) {
    char* p = wp;
    wp += (bytes + 255) & ~(size_t)255;
    return p;
  };
  unsigned int* hist   = (unsigned int*)take((size_t)NBMAX * 4);
  unsigned int* base   = (unsigned int*)take((size_t)(NBMAX + 1) * 4);
  unsigned int* cursor = (unsigned int*)take((size_t)NBMAX * 4);
  unsigned int* bkt    = (unsigned int*)take((size_t)E * 4);
  unsigned short* W1p  = (unsigned short*)take(128 * 128 * 2);
  unsigned short* W2p  = (unsigned short*)take(128 * 128 * 2);
  unsigned short* xb   = (unsigned short*)take((size_t)N * 64 * 2);   // reused as y2
  unsigned short* agg  = (unsigned short*)take((size_t)N * 64 * 2);
  unsigned short* h    = (unsigned short*)take((size_t)N * 128 * 2);
  float* z2            = (float*)take((size_t)N * 64 * 4);
  unsigned short* y2   = xb;  // alias: xb dead after k_mm1

  hipMemsetAsync(hist, 0, (size_t)NBMAX * 4, stream);

  const int n4 = N * 16;
  k_cast<<<(n4 + 255) / 256, 256, 0, stream>>>(x, xb, n4);
  k_bhist<<<(E + 16383) / 16384, 512, 0, stream>>>(dst, hist, E, NB);
  k_scanb<<<1, 64, 0, stream>>>(hist, base, cursor, NB);
  k_part<<<(E + 8191) / 8192, 512, 0, stream>>>(src, dst, cursor, bkt, E, NB);
  k_wprep<<<16, 256, 0, stream>>>(Wl1, Wr1, Wl2, Wr2, W1p, W2p);

  const int nb64 = (N + 63) / 64;
  k_aggs<<<NB, 512, 0, stream>>>(xb, bkt, base, agg, N);
  k_mm1<<<nb64, 256, 0, stream>>>(agg, xb, W1p, b1, h, N);
  k_mm2<<<nb64, 256, 0, stream>>>(h, W2p, y2, z2, N);
  k_aggs<<<NB, 512, 0, stream>>>(y2, bkt, base, agg, N);
  k_sig<<<(N * 16 + 255) / 256, 256, 0, stream>>>(agg, z2, b2, out, N * 16);
}